// Round 1
// baseline (419.405 us; speedup 1.0000x reference)
//
#include <hip/hip_runtime.h>
#include <hip/hip_bf16.h>

#define N_NODES 50000
#define N_EDGES 500000
#define D 128
#define NUM_GRAPHS 512
#define TM 64
#define KC 32

static __device__ __forceinline__ float relu_f(float v) { return v > 0.f ? v : 0.f; }

// ---------------- CSR build ----------------

__global__ void k_count(const int* __restrict__ dst, int* __restrict__ deg) {
  int e = blockIdx.x * 256 + threadIdx.x;
  if (e < N_EDGES) atomicAdd(&deg[dst[e]], 1);
}

__global__ void k_scan1(const int* __restrict__ deg, int* __restrict__ bsum) {
  __shared__ int s[256];
  int t = threadIdx.x;
  int i = blockIdx.x * 256 + t;
  s[t] = (i < N_NODES) ? deg[i] : 0;
  __syncthreads();
  for (int off = 128; off > 0; off >>= 1) {
    if (t < off) s[t] += s[t + off];
    __syncthreads();
  }
  if (t == 0) bsum[blockIdx.x] = s[0];
}

__global__ void k_scan2(int* __restrict__ bsum, int nb) {
  __shared__ int s[256];
  int t = threadIdx.x;
  int v = (t < nb) ? bsum[t] : 0;
  s[t] = v;
  __syncthreads();
  for (int off = 1; off < 256; off <<= 1) {
    int add = (t >= off) ? s[t - off] : 0;
    __syncthreads();
    s[t] += add;
    __syncthreads();
  }
  if (t < nb) bsum[t] = s[t] - v;  // exclusive
}

__global__ void k_scan3(const int* __restrict__ deg, const int* __restrict__ bsum,
                        int* __restrict__ rowptr, int* __restrict__ pos) {
  __shared__ int s[256];
  int t = threadIdx.x;
  int i = blockIdx.x * 256 + t;
  int v = (i < N_NODES) ? deg[i] : 0;
  s[t] = v;
  __syncthreads();
  for (int off = 1; off < 256; off <<= 1) {
    int add = (t >= off) ? s[t - off] : 0;
    __syncthreads();
    s[t] += add;
    __syncthreads();
  }
  int excl = s[t] - v + bsum[blockIdx.x];
  if (i < N_NODES) { rowptr[i] = excl; pos[i] = excl; }
  if (i == N_NODES - 1) rowptr[N_NODES] = excl + v;
}

__global__ void k_bucket(const int* __restrict__ src, const int* __restrict__ dst,
                         int* __restrict__ pos, int* __restrict__ esrc) {
  int e = blockIdx.x * 256 + threadIdx.x;
  if (e < N_EDGES) {
    int slot = atomicAdd(&pos[dst[e]], 1);
    esrc[slot] = src[e];
  }
}

// ---------------- mean aggregation (gather, one wave per node) ----------------

__global__ __launch_bounds__(256) void k_aggregate(
    const float* __restrict__ xin, const int* __restrict__ rowptr,
    const int* __restrict__ esrc, float* __restrict__ agg) {
  int node = (blockIdx.x * 256 + threadIdx.x) >> 6;
  int lane = threadIdx.x & 63;
  if (node >= N_NODES) return;
  int beg = rowptr[node], end = rowptr[node + 1];
  float2 acc = make_float2(0.f, 0.f);
  int e = beg;
  for (; e + 2 <= end; e += 2) {
    int s0 = esrc[e], s1 = esrc[e + 1];
    float2 v0 = *(const float2*)&xin[s0 * D + lane * 2];
    float2 v1 = *(const float2*)&xin[s1 * D + lane * 2];
    acc.x += v0.x + v1.x;
    acc.y += v0.y + v1.y;
  }
  if (e < end) {
    int s0 = esrc[e];
    float2 v0 = *(const float2*)&xin[s0 * D + lane * 2];
    acc.x += v0.x;
    acc.y += v0.y;
  }
  float inv = 1.0f / fmaxf((float)(end - beg), 1.0f);
  *(float2*)&agg[node * D + lane * 2] = make_float2(acc.x * inv, acc.y * inv);
}

// ---------------- GEMM: Y = relu(A @ Wl^T + X @ Wr^T), fused segment_max pool ----------------

__global__ __launch_bounds__(256) void k_gemm_pool(
    const float* __restrict__ A, const float* __restrict__ X,
    const float* __restrict__ Wl, const float* __restrict__ Wr,
    const int* __restrict__ batch, float* __restrict__ Y /*nullable*/,
    float* __restrict__ pool, int col_ofs) {
  __shared__ float sA[TM][KC + 4];   // +4 pad keeps float4 align, breaks bank stride
  __shared__ float sX[TM][KC + 4];
  __shared__ float sWl[KC][D];       // transposed: [k][j]
  __shared__ float sWr[KC][D];

  const int tid = threadIdx.x;
  const int tx = tid & 15;   // 16 col groups: cols tx*4..tx*4+3 and 64+tx*4..
  const int ty = tid >> 4;   // 16 row groups: rows ty*4..ty*4+3
  const int row0 = blockIdx.x * TM;

  float acc[4][8];
#pragma unroll
  for (int i = 0; i < 4; ++i)
#pragma unroll
    for (int c = 0; c < 8; ++c) acc[i][c] = 0.f;

  for (int k0 = 0; k0 < D; k0 += KC) {
    // stage A, X tiles (64 rows x 32 k)
#pragma unroll
    for (int v = 0; v < 2; ++v) {
      int vid = tid + v * 256;
      int r = vid >> 3;
      int q = vid & 7;
      int row = row0 + r;
      float4 va = make_float4(0.f, 0.f, 0.f, 0.f);
      float4 vx = va;
      if (row < N_NODES) {
        va = *(const float4*)&A[row * D + k0 + q * 4];
        vx = *(const float4*)&X[row * D + k0 + q * 4];
      }
      *(float4*)&sA[r][q * 4] = va;
      *(float4*)&sX[r][q * 4] = vx;
    }
    // stage weights transposed (128 j x 32 k)
    {
      int j = tid >> 1;
      int half = tid & 1;
#pragma unroll
      for (int q = 0; q < 4; ++q) {
        int kk = half * 16 + q * 4;
        float4 wl = *(const float4*)&Wl[j * D + k0 + kk];
        float4 wr = *(const float4*)&Wr[j * D + k0 + kk];
        sWl[kk + 0][j] = wl.x; sWl[kk + 1][j] = wl.y;
        sWl[kk + 2][j] = wl.z; sWl[kk + 3][j] = wl.w;
        sWr[kk + 0][j] = wr.x; sWr[kk + 1][j] = wr.y;
        sWr[kk + 2][j] = wr.z; sWr[kk + 3][j] = wr.w;
      }
    }
    __syncthreads();
#pragma unroll 8
    for (int k = 0; k < KC; ++k) {
      float4 wl0 = *(const float4*)&sWl[k][tx * 4];
      float4 wl1 = *(const float4*)&sWl[k][64 + tx * 4];
      float4 wr0 = *(const float4*)&sWr[k][tx * 4];
      float4 wr1 = *(const float4*)&sWr[k][64 + tx * 4];
#pragma unroll
      for (int i = 0; i < 4; ++i) {
        float a = sA[ty * 4 + i][k];
        float b = sX[ty * 4 + i][k];
        acc[i][0] += a * wl0.x + b * wr0.x;
        acc[i][1] += a * wl0.y + b * wr0.y;
        acc[i][2] += a * wl0.z + b * wr0.z;
        acc[i][3] += a * wl0.w + b * wr0.w;
        acc[i][4] += a * wl1.x + b * wr1.x;
        acc[i][5] += a * wl1.y + b * wr1.y;
        acc[i][6] += a * wl1.z + b * wr1.z;
        acc[i][7] += a * wl1.w + b * wr1.w;
      }
    }
    __syncthreads();
  }

  // epilogue: relu, optional write of node features, fused max-pool into d_out
#pragma unroll
  for (int i = 0; i < 4; ++i) {
    int row = row0 + ty * 4 + i;
    if (row >= N_NODES) continue;
    int g = batch[row];
    float r0 = relu_f(acc[i][0]), r1 = relu_f(acc[i][1]);
    float r2 = relu_f(acc[i][2]), r3 = relu_f(acc[i][3]);
    float r4 = relu_f(acc[i][4]), r5 = relu_f(acc[i][5]);
    float r6 = relu_f(acc[i][6]), r7 = relu_f(acc[i][7]);
    if (Y != nullptr) {
      *(float4*)&Y[row * D + tx * 4] = make_float4(r0, r1, r2, r3);
      *(float4*)&Y[row * D + 64 + tx * 4] = make_float4(r4, r5, r6, r7);
    }
    // relu output >= 0, so float bit pattern is monotone as unsigned
    unsigned int* P = (unsigned int*)(pool + (size_t)g * (2 * D) + col_ofs);
    atomicMax(&P[tx * 4 + 0], __float_as_uint(r0));
    atomicMax(&P[tx * 4 + 1], __float_as_uint(r1));
    atomicMax(&P[tx * 4 + 2], __float_as_uint(r2));
    atomicMax(&P[tx * 4 + 3], __float_as_uint(r3));
    atomicMax(&P[64 + tx * 4 + 0], __float_as_uint(r4));
    atomicMax(&P[64 + tx * 4 + 1], __float_as_uint(r5));
    atomicMax(&P[64 + tx * 4 + 2], __float_as_uint(r6));
    atomicMax(&P[64 + tx * 4 + 3], __float_as_uint(r7));
  }
}

// ---------------- launch ----------------

extern "C" void kernel_launch(void* const* d_in, const int* in_sizes, int n_in,
                              void* d_out, int out_size, void* d_ws, size_t ws_size,
                              hipStream_t stream) {
  const float* x = (const float*)d_in[0];
  const int* ei = (const int*)d_in[1];
  const int* src = ei;               // edge_index[0]
  const int* dst = ei + N_EDGES;     // edge_index[1]
  const int* batch = (const int*)d_in[2];
  const float* Wl1 = (const float*)d_in[3];
  const float* Wr1 = (const float*)d_in[4];
  const float* Wl2 = (const float*)d_in[5];
  const float* Wr2 = (const float*)d_in[6];
  float* out = (float*)d_out;

  char* ws = (char*)d_ws;
  size_t off = 0;
  auto alloc = [&](size_t bytes) -> void* {
    void* p = ws + off;
    off += (bytes + 511) & ~(size_t)511;
    return p;
  };
  int* deg = (int*)alloc((size_t)N_NODES * 4);
  int* rowptr = (int*)alloc((size_t)(N_NODES + 1) * 4);
  int* pos = (int*)alloc((size_t)N_NODES * 4);
  int* bsum = (int*)alloc(256 * 4);
  int* esrc = (int*)alloc((size_t)N_EDGES * 4);
  float* agg = (float*)alloc((size_t)N_NODES * D * 4);
  float* x1 = (float*)alloc((size_t)N_NODES * D * 4);
  (void)ws_size; (void)in_sizes; (void)n_in; (void)out_size;

  (void)hipMemsetAsync(deg, 0, (size_t)N_NODES * 4, stream);
  (void)hipMemsetAsync(d_out, 0, (size_t)NUM_GRAPHS * 2 * D * 4, stream);

  int nb = (N_NODES + 255) / 256;  // 196
  k_count<<<(N_EDGES + 255) / 256, 256, 0, stream>>>(dst, deg);
  k_scan1<<<nb, 256, 0, stream>>>(deg, bsum);
  k_scan2<<<1, 256, 0, stream>>>(bsum, nb);
  k_scan3<<<nb, 256, 0, stream>>>(deg, bsum, rowptr, pos);
  k_bucket<<<(N_EDGES + 255) / 256, 256, 0, stream>>>(src, dst, pos, esrc);

  int agg_blocks = (N_NODES + 3) / 4;  // 4 waves (nodes) per block
  int gemm_blocks = (N_NODES + TM - 1) / TM;

  // layer 1
  k_aggregate<<<agg_blocks, 256, 0, stream>>>(x, rowptr, esrc, agg);
  k_gemm_pool<<<gemm_blocks, 256, 0, stream>>>(agg, x, Wl1, Wr1, batch, x1, out, 0);
  // layer 2 (x2 never materialized; pooled directly)
  k_aggregate<<<agg_blocks, 256, 0, stream>>>(x1, rowptr, esrc, agg);
  k_gemm_pool<<<gemm_blocks, 256, 0, stream>>>(agg, x1, Wl2, Wr2, batch, nullptr, out, D);
}

// Round 2
// 310.430 us; speedup vs baseline: 1.3510x; 1.3510x over previous
//
#include <hip/hip_runtime.h>
#include <hip/hip_bf16.h>

#define N_NODES 50000
#define N_EDGES 500000
#define D 128
#define NUM_GRAPHS 512
#define TM 64
#define KC 32

static __device__ __forceinline__ float relu_f(float v) { return v > 0.f ? v : 0.f; }

// ---------------- CSR build ----------------

__global__ void k_count(const int* __restrict__ dst, int* __restrict__ deg) {
  int e = blockIdx.x * 256 + threadIdx.x;
  if (e < N_EDGES) atomicAdd(&deg[dst[e]], 1);
}

__global__ void k_scan1(const int* __restrict__ deg, int* __restrict__ bsum) {
  __shared__ int s[256];
  int t = threadIdx.x;
  int i = blockIdx.x * 256 + t;
  s[t] = (i < N_NODES) ? deg[i] : 0;
  __syncthreads();
  for (int off = 128; off > 0; off >>= 1) {
    if (t < off) s[t] += s[t + off];
    __syncthreads();
  }
  if (t == 0) bsum[blockIdx.x] = s[0];
}

__global__ void k_scan2(int* __restrict__ bsum, int nb) {
  __shared__ int s[256];
  int t = threadIdx.x;
  int v = (t < nb) ? bsum[t] : 0;
  s[t] = v;
  __syncthreads();
  for (int off = 1; off < 256; off <<= 1) {
    int add = (t >= off) ? s[t - off] : 0;
    __syncthreads();
    s[t] += add;
    __syncthreads();
  }
  if (t < nb) bsum[t] = s[t] - v;  // exclusive
}

__global__ void k_scan3(const int* __restrict__ deg, const int* __restrict__ bsum,
                        int* __restrict__ rowptr, int* __restrict__ pos) {
  __shared__ int s[256];
  int t = threadIdx.x;
  int i = blockIdx.x * 256 + t;
  int v = (i < N_NODES) ? deg[i] : 0;
  s[t] = v;
  __syncthreads();
  for (int off = 1; off < 256; off <<= 1) {
    int add = (t >= off) ? s[t - off] : 0;
    __syncthreads();
    s[t] += add;
    __syncthreads();
  }
  int excl = s[t] - v + bsum[blockIdx.x];
  if (i < N_NODES) { rowptr[i] = excl; pos[i] = excl; }
  if (i == N_NODES - 1) rowptr[N_NODES] = excl + v;
}

__global__ void k_bucket(const int* __restrict__ src, const int* __restrict__ dst,
                         int* __restrict__ pos, int* __restrict__ esrc) {
  int e = blockIdx.x * 256 + threadIdx.x;
  if (e < N_EDGES) {
    int slot = atomicAdd(&pos[dst[e]], 1);
    esrc[slot] = src[e];
  }
}

// ---------------- graph ranges (batch is sorted) ----------------

__global__ void k_ranges(const int* __restrict__ batch, int* __restrict__ gstart) {
  int i = blockIdx.x * 256 + threadIdx.x;
  if (i >= N_NODES) return;
  int b = batch[i];
  int prev = (i == 0) ? -1 : batch[i - 1];
  for (int g = prev + 1; g <= b; ++g) gstart[g] = i;
  if (i == N_NODES - 1)
    for (int g = b + 1; g <= NUM_GRAPHS; ++g) gstart[g] = N_NODES;
}

// ---------------- mean aggregation (gather, one wave per node) ----------------

__global__ __launch_bounds__(256) void k_aggregate(
    const float* __restrict__ xin, const int* __restrict__ rowptr,
    const int* __restrict__ esrc, float* __restrict__ agg) {
  int node = (blockIdx.x * 256 + threadIdx.x) >> 6;
  int lane = threadIdx.x & 63;
  if (node >= N_NODES) return;
  int beg = rowptr[node], end = rowptr[node + 1];
  float2 acc = make_float2(0.f, 0.f);
  int e = beg;
  for (; e + 2 <= end; e += 2) {
    int s0 = esrc[e], s1 = esrc[e + 1];
    float2 v0 = *(const float2*)&xin[s0 * D + lane * 2];
    float2 v1 = *(const float2*)&xin[s1 * D + lane * 2];
    acc.x += v0.x + v1.x;
    acc.y += v0.y + v1.y;
  }
  if (e < end) {
    int s0 = esrc[e];
    float2 v0 = *(const float2*)&xin[s0 * D + lane * 2];
    acc.x += v0.x;
    acc.y += v0.y;
  }
  float inv = 1.0f / fmaxf((float)(end - beg), 1.0f);
  *(float2*)&agg[node * D + lane * 2] = make_float2(acc.x * inv, acc.y * inv);
}

// ---------------- GEMM: Y = relu(A @ Wl^T + X @ Wr^T) ----------------

__global__ __launch_bounds__(256) void k_gemm(
    const float* __restrict__ A, const float* __restrict__ X,
    const float* __restrict__ Wl, const float* __restrict__ Wr,
    float* __restrict__ Y) {
  __shared__ float sA[TM][KC + 4];
  __shared__ float sX[TM][KC + 4];
  __shared__ float sWl[KC][D];   // transposed: [k][j]
  __shared__ float sWr[KC][D];

  const int tid = threadIdx.x;
  const int tx = tid & 15;   // cols tx*4..+3 and 64+tx*4..+3
  const int ty = tid >> 4;   // rows ty*4..+3
  const int row0 = blockIdx.x * TM;

  float acc[4][8];
#pragma unroll
  for (int i = 0; i < 4; ++i)
#pragma unroll
    for (int c = 0; c < 8; ++c) acc[i][c] = 0.f;

  for (int k0 = 0; k0 < D; k0 += KC) {
#pragma unroll
    for (int v = 0; v < 2; ++v) {
      int vid = tid + v * 256;
      int r = vid >> 3;
      int q = vid & 7;
      int row = row0 + r;
      float4 va = make_float4(0.f, 0.f, 0.f, 0.f);
      float4 vx = va;
      if (row < N_NODES) {
        va = *(const float4*)&A[row * D + k0 + q * 4];
        vx = *(const float4*)&X[row * D + k0 + q * 4];
      }
      *(float4*)&sA[r][q * 4] = va;
      *(float4*)&sX[r][q * 4] = vx;
    }
    {
      int j = tid >> 1;
      int half = tid & 1;
#pragma unroll
      for (int q = 0; q < 4; ++q) {
        int kk = half * 16 + q * 4;
        float4 wl = *(const float4*)&Wl[j * D + k0 + kk];
        float4 wr = *(const float4*)&Wr[j * D + k0 + kk];
        sWl[kk + 0][j] = wl.x; sWl[kk + 1][j] = wl.y;
        sWl[kk + 2][j] = wl.z; sWl[kk + 3][j] = wl.w;
        sWr[kk + 0][j] = wr.x; sWr[kk + 1][j] = wr.y;
        sWr[kk + 2][j] = wr.z; sWr[kk + 3][j] = wr.w;
      }
    }
    __syncthreads();
#pragma unroll 8
    for (int k = 0; k < KC; ++k) {
      float4 wl0 = *(const float4*)&sWl[k][tx * 4];
      float4 wl1 = *(const float4*)&sWl[k][64 + tx * 4];
      float4 wr0 = *(const float4*)&sWr[k][tx * 4];
      float4 wr1 = *(const float4*)&sWr[k][64 + tx * 4];
#pragma unroll
      for (int i = 0; i < 4; ++i) {
        float a = sA[ty * 4 + i][k];
        float b = sX[ty * 4 + i][k];
        acc[i][0] += a * wl0.x + b * wr0.x;
        acc[i][1] += a * wl0.y + b * wr0.y;
        acc[i][2] += a * wl0.z + b * wr0.z;
        acc[i][3] += a * wl0.w + b * wr0.w;
        acc[i][4] += a * wl1.x + b * wr1.x;
        acc[i][5] += a * wl1.y + b * wr1.y;
        acc[i][6] += a * wl1.z + b * wr1.z;
        acc[i][7] += a * wl1.w + b * wr1.w;
      }
    }
    __syncthreads();
  }

#pragma unroll
  for (int i = 0; i < 4; ++i) {
    int row = row0 + ty * 4 + i;
    if (row >= N_NODES) continue;
    float4 lo = make_float4(relu_f(acc[i][0]), relu_f(acc[i][1]),
                            relu_f(acc[i][2]), relu_f(acc[i][3]));
    float4 hi = make_float4(relu_f(acc[i][4]), relu_f(acc[i][5]),
                            relu_f(acc[i][6]), relu_f(acc[i][7]));
    *(float4*)&Y[row * D + tx * 4] = lo;
    *(float4*)&Y[row * D + 64 + tx * 4] = hi;
  }
}

// ---------------- segment-max pool (no atomics; batch sorted) ----------------

__global__ __launch_bounds__(256) void k_pool(
    const float* __restrict__ x1, const float* __restrict__ x2,
    const int* __restrict__ gstart, float* __restrict__ out) {
  int g = blockIdx.x;
  int tid = threadIdx.x;
  int beg = gstart[g], end = gstart[g + 1];
  const float* srcp = (tid < D) ? (x1 + tid) : (x2 + (tid - D));
  float m = 0.f;   // relu output >= 0; empty graphs -> 0 matches isfinite guard
  int r = beg;
  for (; r + 2 <= end; r += 2) {
    float a = srcp[(size_t)r * D];
    float b = srcp[(size_t)(r + 1) * D];
    m = fmaxf(m, fmaxf(a, b));
  }
  if (r < end) m = fmaxf(m, srcp[(size_t)r * D]);
  out[g * (2 * D) + tid] = m;
}

// ---------------- launch ----------------

extern "C" void kernel_launch(void* const* d_in, const int* in_sizes, int n_in,
                              void* d_out, int out_size, void* d_ws, size_t ws_size,
                              hipStream_t stream) {
  const float* x = (const float*)d_in[0];
  const int* ei = (const int*)d_in[1];
  const int* src = ei;               // edge_index[0]
  const int* dst = ei + N_EDGES;     // edge_index[1]
  const int* batch = (const int*)d_in[2];
  const float* Wl1 = (const float*)d_in[3];
  const float* Wr1 = (const float*)d_in[4];
  const float* Wl2 = (const float*)d_in[5];
  const float* Wr2 = (const float*)d_in[6];
  float* out = (float*)d_out;

  char* ws = (char*)d_ws;
  size_t off = 0;
  auto alloc = [&](size_t bytes) -> void* {
    void* p = ws + off;
    off += (bytes + 511) & ~(size_t)511;
    return p;
  };
  int* deg = (int*)alloc((size_t)N_NODES * 4);
  int* rowptr = (int*)alloc((size_t)(N_NODES + 1) * 4);
  int* pos = (int*)alloc((size_t)N_NODES * 4);
  int* bsum = (int*)alloc(256 * 4);
  int* gstart = (int*)alloc((size_t)(NUM_GRAPHS + 1) * 4);
  int* esrc = (int*)alloc((size_t)N_EDGES * 4);
  float* agg = (float*)alloc((size_t)N_NODES * D * 4);  // reused: agg1, agg2, then x2
  float* x1 = (float*)alloc((size_t)N_NODES * D * 4);
  (void)ws_size; (void)in_sizes; (void)n_in; (void)out_size;

  (void)hipMemsetAsync(deg, 0, (size_t)N_NODES * 4, stream);

  int nb = (N_NODES + 255) / 256;  // 196
  k_count<<<(N_EDGES + 255) / 256, 256, 0, stream>>>(dst, deg);
  k_scan1<<<nb, 256, 0, stream>>>(deg, bsum);
  k_scan2<<<1, 256, 0, stream>>>(bsum, nb);
  k_scan3<<<nb, 256, 0, stream>>>(deg, bsum, rowptr, pos);
  k_bucket<<<(N_EDGES + 255) / 256, 256, 0, stream>>>(src, dst, pos, esrc);
  k_ranges<<<nb, 256, 0, stream>>>(batch, gstart);

  int agg_blocks = (N_NODES + 3) / 4;
  int gemm_blocks = (N_NODES + TM - 1) / TM;

  // layer 1
  k_aggregate<<<agg_blocks, 256, 0, stream>>>(x, rowptr, esrc, agg);
  k_gemm<<<gemm_blocks, 256, 0, stream>>>(agg, x, Wl1, Wr1, x1);
  // layer 2: agg buffer reused for agg2, then x2 written in-place
  // (safe: each gemm block reads only its own 64 A-rows, all before its epilogue)
  k_aggregate<<<agg_blocks, 256, 0, stream>>>(x1, rowptr, esrc, agg);
  k_gemm<<<gemm_blocks, 256, 0, stream>>>(agg, x1, Wl2, Wr2, agg);
  // pool: x1 -> cols [0,128), x2(=agg) -> cols [128,256)
  k_pool<<<NUM_GRAPHS, 256, 0, stream>>>(x1, agg, gstart, out);
}

// Round 3
// 182.422 us; speedup vs baseline: 2.2991x; 1.7017x over previous
//
#include <hip/hip_runtime.h>
#include <hip/hip_bf16.h>

#define N_NODES 50000
#define N_EDGES 500000
#define D 128
#define NUM_GRAPHS 512
#define BM 128

typedef __attribute__((ext_vector_type(8))) short bf16x8;
typedef __attribute__((ext_vector_type(4))) float f32x4;

static __device__ __forceinline__ unsigned short f2b(float f) {
  __hip_bfloat16 h = __float2bfloat16(f);
  return *reinterpret_cast<unsigned short*>(&h);
}
static __device__ __forceinline__ float blo(unsigned int p) {
  return __uint_as_float(p << 16);
}
static __device__ __forceinline__ float bhi(unsigned int p) {
  return __uint_as_float(p & 0xffff0000u);
}

// ---------------- CSR build ----------------

__global__ void k_count(const int* __restrict__ dst, int* __restrict__ deg) {
  int e = blockIdx.x * 256 + threadIdx.x;
  if (e < N_EDGES) atomicAdd(&deg[dst[e]], 1);
}

__global__ void k_scan1(const int* __restrict__ deg, int* __restrict__ bsum) {
  __shared__ int s[256];
  int t = threadIdx.x;
  int i = blockIdx.x * 256 + t;
  s[t] = (i < N_NODES) ? deg[i] : 0;
  __syncthreads();
  for (int off = 128; off > 0; off >>= 1) {
    if (t < off) s[t] += s[t + off];
    __syncthreads();
  }
  if (t == 0) bsum[blockIdx.x] = s[0];
}

__global__ void k_scan2(int* __restrict__ bsum, int nb) {
  __shared__ int s[256];
  int t = threadIdx.x;
  int v = (t < nb) ? bsum[t] : 0;
  s[t] = v;
  __syncthreads();
  for (int off = 1; off < 256; off <<= 1) {
    int add = (t >= off) ? s[t - off] : 0;
    __syncthreads();
    s[t] += add;
    __syncthreads();
  }
  if (t < nb) bsum[t] = s[t] - v;  // exclusive
}

__global__ void k_scan3(const int* __restrict__ deg, const int* __restrict__ bsum,
                        int* __restrict__ rowptr, int* __restrict__ pos) {
  __shared__ int s[256];
  int t = threadIdx.x;
  int i = blockIdx.x * 256 + t;
  int v = (i < N_NODES) ? deg[i] : 0;
  s[t] = v;
  __syncthreads();
  for (int off = 1; off < 256; off <<= 1) {
    int add = (t >= off) ? s[t - off] : 0;
    __syncthreads();
    s[t] += add;
    __syncthreads();
  }
  int excl = s[t] - v + bsum[blockIdx.x];
  if (i < N_NODES) { rowptr[i] = excl; pos[i] = excl; }
  if (i == N_NODES - 1) rowptr[N_NODES] = excl + v;
}

__global__ void k_bucket(const int* __restrict__ src, const int* __restrict__ dst,
                         int* __restrict__ pos, int* __restrict__ esrc) {
  int e = blockIdx.x * 256 + threadIdx.x;
  if (e < N_EDGES) {
    int slot = atomicAdd(&pos[dst[e]], 1);
    esrc[slot] = src[e];
  }
}

// ---------------- graph ranges (batch is sorted) ----------------

__global__ void k_ranges(const int* __restrict__ batch, int* __restrict__ gstart) {
  int i = blockIdx.x * 256 + threadIdx.x;
  if (i >= N_NODES) return;
  int b = batch[i];
  int prev = (i == 0) ? -1 : batch[i - 1];
  for (int g = prev + 1; g <= b; ++g) gstart[g] = i;
  if (i == N_NODES - 1)
    for (int g = b + 1; g <= NUM_GRAPHS; ++g) gstart[g] = N_NODES;
}

// ---------------- fp32 -> bf16 convert ----------------

__global__ void k_cvt(const float* __restrict__ x, unsigned short* __restrict__ xb) {
  int i = (blockIdx.x * 256 + threadIdx.x) * 4;
  if (i >= N_NODES * D) return;
  float4 f = *(const float4*)&x[i];
  ushort4 o = make_ushort4(f2b(f.x), f2b(f.y), f2b(f.z), f2b(f.w));
  *(ushort4*)&xb[i] = o;
}

// ---------------- mean aggregation (bf16 gather, one wave per node) ----------------

__global__ __launch_bounds__(256) void k_agg(
    const unsigned short* __restrict__ xb, const int* __restrict__ rowptr,
    const int* __restrict__ esrc, unsigned short* __restrict__ aggb) {
  int node = (blockIdx.x * 256 + threadIdx.x) >> 6;
  int lane = threadIdx.x & 63;
  if (node >= N_NODES) return;
  int beg = rowptr[node], end = rowptr[node + 1];
  float ax = 0.f, ay = 0.f;
  int e = beg;
  for (; e + 4 <= end; e += 4) {
    unsigned int p0 = *(const unsigned int*)&xb[(size_t)esrc[e] * D + lane * 2];
    unsigned int p1 = *(const unsigned int*)&xb[(size_t)esrc[e + 1] * D + lane * 2];
    unsigned int p2 = *(const unsigned int*)&xb[(size_t)esrc[e + 2] * D + lane * 2];
    unsigned int p3 = *(const unsigned int*)&xb[(size_t)esrc[e + 3] * D + lane * 2];
    ax += blo(p0) + blo(p1) + blo(p2) + blo(p3);
    ay += bhi(p0) + bhi(p1) + bhi(p2) + bhi(p3);
  }
  for (; e < end; ++e) {
    unsigned int p = *(const unsigned int*)&xb[(size_t)esrc[e] * D + lane * 2];
    ax += blo(p);
    ay += bhi(p);
  }
  float inv = 1.f / fmaxf((float)(end - beg), 1.f);
  unsigned int o = (unsigned int)f2b(ax * inv) | ((unsigned int)f2b(ay * inv) << 16);
  *(unsigned int*)&aggb[(size_t)node * D + lane * 2] = o;
}

// ---------------- MFMA GEMM: Yb = relu([Ab|Xb] @ [Wl|Wr]^T) as bf16 ----------------
// No __restrict__ on Ab/Yb: layer 2 aliases them (per-block same rows only).

__global__ __launch_bounds__(512) void k_gemm(
    const unsigned short* Ab, const unsigned short* __restrict__ Xb,
    const float* __restrict__ Wl, const float* __restrict__ Wr,
    unsigned short* Yb) {
  __shared__ unsigned short Wlds[32768];  // 64KB: weights [j][k] bf16, XOR-swizzled
  const int tid = threadIdx.x;
  const int w = tid >> 6, lane = tid & 63;
  const int lr = lane & 15, lh = lane >> 4;
  const int row0 = blockIdx.x * BM;
  const int row = row0 + w * 16 + lr;

  // A fragments: row `row`, k in [0,256): first half Ab, second half Xb
  bf16x8 a[8];
  if (row < N_NODES) {
    const unsigned short* ar = Ab + (size_t)row * D;
    const unsigned short* xr = Xb + (size_t)row * D;
#pragma unroll
    for (int kk = 0; kk < 4; ++kk)
      a[kk] = *(const bf16x8*)(ar + kk * 32 + lh * 8);
#pragma unroll
    for (int kk = 0; kk < 4; ++kk)
      a[4 + kk] = *(const bf16x8*)(xr + kk * 32 + lh * 8);
  } else {
#pragma unroll
    for (int kk = 0; kk < 8; ++kk)
      a[kk] = (bf16x8){0, 0, 0, 0, 0, 0, 0, 0};
  }

  // stage combined weight row j: k<128 from Wl, k>=128 from Wr; swizzle byte^=(j&7)<<4
  {
    int j = tid >> 2, quarter = tid & 3;
    const float* srcp = (quarter < 2) ? (Wl + j * D + quarter * 64)
                                      : (Wr + j * D + (quarter - 2) * 64);
#pragma unroll
    for (int q = 0; q < 8; ++q) {
      float4 f0 = *(const float4*)(srcp + q * 8);
      float4 f1 = *(const float4*)(srcp + q * 8 + 4);
      bf16x8 wv;
      wv[0] = (short)f2b(f0.x); wv[1] = (short)f2b(f0.y);
      wv[2] = (short)f2b(f0.z); wv[3] = (short)f2b(f0.w);
      wv[4] = (short)f2b(f1.x); wv[5] = (short)f2b(f1.y);
      wv[6] = (short)f2b(f1.z); wv[7] = (short)f2b(f1.w);
      int byteofs = j * 512 + ((quarter * 128 + q * 16) ^ ((j & 7) << 4));
      *(bf16x8*)((char*)Wlds + byteofs) = wv;
    }
  }
  __syncthreads();

  f32x4 acc[8];
#pragma unroll
  for (int jt = 0; jt < 8; ++jt) acc[jt] = (f32x4){0.f, 0.f, 0.f, 0.f};

#pragma unroll
  for (int jt = 0; jt < 8; ++jt) {
    int jj = jt * 16 + lr;
    const char* wbase = (const char*)Wlds + jj * 512;
    int sw = (jj & 7) << 4;
#pragma unroll
    for (int kk = 0; kk < 8; ++kk) {
      bf16x8 b = *(const bf16x8*)(wbase + ((kk * 64 + lh * 16) ^ sw));
      acc[jt] = __builtin_amdgcn_mfma_f32_16x16x32_bf16(a[kk], b, acc[jt], 0, 0, 0);
    }
  }

  __syncthreads();  // all waves done reading weights; reuse LDS for output tile
  // write relu(acc) as bf16 tile [128 rows][128 cols], swizzled
#pragma unroll
  for (int jt = 0; jt < 8; ++jt) {
#pragma unroll
    for (int r = 0; r < 4; ++r) {
      int rl = w * 16 + lh * 4 + r;
      int col = jt * 16 + lr;
      float v = acc[jt][r];
      v = v > 0.f ? v : 0.f;
      int byteofs = rl * 256 + ((col * 2) ^ ((rl & 7) << 4));
      *(unsigned short*)((char*)Wlds + byteofs) = f2b(v);
    }
  }
  __syncthreads();
  // coalesced bf16x8 stores
  {
    int rl = tid >> 2, c0 = (tid & 3) * 64;  // c0 in bytes
    int grow = row0 + rl;
    if (grow < N_NODES) {
#pragma unroll
      for (int cc = 0; cc < 4; ++cc) {
        int byteofs = rl * 256 + ((c0 + cc * 16) ^ ((rl & 7) << 4));
        bf16x8 v = *(const bf16x8*)((char*)Wlds + byteofs);
        *(bf16x8*)&Yb[(size_t)grow * D + (c0 + cc * 16) / 2] = v;
      }
    }
  }
}

// ---------------- segment-max pool (bf16 in, fp32 out) ----------------

__global__ __launch_bounds__(256) void k_pool(
    const unsigned short* __restrict__ x1b, const unsigned short* __restrict__ x2b,
    const int* __restrict__ gstart, float* __restrict__ out) {
  int g = blockIdx.x, tid = threadIdx.x;
  int beg = gstart[g], end = gstart[g + 1];
  const unsigned short* base = (tid < D) ? (x1b + tid) : (x2b + (tid - D));
  float m = 0.f;  // relu >= 0; empty graph -> 0 matches isfinite guard
  int r = beg;
  for (; r + 2 <= end; r += 2) {
    float a = __uint_as_float((unsigned int)base[(size_t)r * D] << 16);
    float b = __uint_as_float((unsigned int)base[(size_t)(r + 1) * D] << 16);
    m = fmaxf(m, fmaxf(a, b));
  }
  if (r < end)
    m = fmaxf(m, __uint_as_float((unsigned int)base[(size_t)r * D] << 16));
  out[g * (2 * D) + tid] = m;
}

// ---------------- launch ----------------

extern "C" void kernel_launch(void* const* d_in, const int* in_sizes, int n_in,
                              void* d_out, int out_size, void* d_ws, size_t ws_size,
                              hipStream_t stream) {
  const float* x = (const float*)d_in[0];
  const int* ei = (const int*)d_in[1];
  const int* src = ei;               // edge_index[0]
  const int* dst = ei + N_EDGES;     // edge_index[1]
  const int* batch = (const int*)d_in[2];
  const float* Wl1 = (const float*)d_in[3];
  const float* Wr1 = (const float*)d_in[4];
  const float* Wl2 = (const float*)d_in[5];
  const float* Wr2 = (const float*)d_in[6];
  float* out = (float*)d_out;

  char* ws = (char*)d_ws;
  size_t off = 0;
  auto alloc = [&](size_t bytes) -> void* {
    void* p = ws + off;
    off += (bytes + 511) & ~(size_t)511;
    return p;
  };
  int* deg = (int*)alloc((size_t)N_NODES * 4);
  int* rowptr = (int*)alloc((size_t)(N_NODES + 1) * 4);
  int* pos = (int*)alloc((size_t)N_NODES * 4);
  int* bsum = (int*)alloc(256 * 4);
  int* gstart = (int*)alloc((size_t)(NUM_GRAPHS + 1) * 4);
  int* esrc = (int*)alloc((size_t)N_EDGES * 4);
  unsigned short* xb = (unsigned short*)alloc((size_t)N_NODES * D * 2);
  unsigned short* aggb = (unsigned short*)alloc((size_t)N_NODES * D * 2);  // agg1, agg2, then x2
  unsigned short* x1b = (unsigned short*)alloc((size_t)N_NODES * D * 2);
  (void)ws_size; (void)in_sizes; (void)n_in; (void)out_size;

  (void)hipMemsetAsync(deg, 0, (size_t)N_NODES * 4, stream);

  int nb = (N_NODES + 255) / 256;  // 196
  k_count<<<(N_EDGES + 255) / 256, 256, 0, stream>>>(dst, deg);
  k_scan1<<<nb, 256, 0, stream>>>(deg, bsum);
  k_scan2<<<1, 256, 0, stream>>>(bsum, nb);
  k_scan3<<<nb, 256, 0, stream>>>(deg, bsum, rowptr, pos);
  k_bucket<<<(N_EDGES + 255) / 256, 256, 0, stream>>>(src, dst, pos, esrc);
  k_ranges<<<nb, 256, 0, stream>>>(batch, gstart);
  k_cvt<<<(N_NODES * D / 4 + 255) / 256, 256, 0, stream>>>(x, xb);

  int agg_blocks = (N_NODES * 64 + 255) / 256;
  int gemm_blocks = (N_NODES + BM - 1) / BM;  // 391

  // layer 1
  k_agg<<<agg_blocks, 256, 0, stream>>>(xb, rowptr, esrc, aggb);
  k_gemm<<<gemm_blocks, 512, 0, stream>>>(aggb, xb, Wl1, Wr1, x1b);
  // layer 2: aggb reused for agg2, then x2 written in place (per-block same rows)
  k_agg<<<agg_blocks, 256, 0, stream>>>(x1b, rowptr, esrc, aggb);
  k_gemm<<<gemm_blocks, 512, 0, stream>>>(aggb, x1b, Wl2, Wr2, aggb);
  // pool: x1 -> cols [0,128), x2(=aggb) -> cols [128,256)
  k_pool<<<NUM_GRAPHS, 256, 0, stream>>>(x1b, aggb, gstart, out);
}

// Round 4
// 170.587 us; speedup vs baseline: 2.4586x; 1.0694x over previous
//
#include <hip/hip_runtime.h>
#include <hip/hip_bf16.h>

#define N_NODES 50000
#define N_EDGES 500000
#define D 128
#define NUM_GRAPHS 512
#define BM 128
#define NB_NODES 196      // ceil(50000/256)
#define CVT_BLOCKS 6250   // 50000*128/(4*256)

typedef __attribute__((ext_vector_type(8))) short bf16x8;
typedef __attribute__((ext_vector_type(4))) float f32x4;

static __device__ __forceinline__ unsigned short f2b(float f) {
  __hip_bfloat16 h = __float2bfloat16(f);
  return *reinterpret_cast<unsigned short*>(&h);
}
static __device__ __forceinline__ float blo(unsigned int p) {
  return __uint_as_float(p << 16);
}
static __device__ __forceinline__ float bhi(unsigned int p) {
  return __uint_as_float(p & 0xffff0000u);
}

// ---------------- fused prep: zero deg + graph ranges + fp32->bf16 convert ----------------

__global__ __launch_bounds__(256) void k_prep(
    const float* __restrict__ x, unsigned short* __restrict__ xb,
    const int* __restrict__ batch, int* __restrict__ gstart,
    int* __restrict__ deg) {
  int b = blockIdx.x;
  if (b < NB_NODES) {
    int i = b * 256 + threadIdx.x;
    if (i < N_NODES) {
      deg[i] = 0;
      int bb = batch[i];
      int prev = (i == 0) ? -1 : batch[i - 1];
      for (int g = prev + 1; g <= bb; ++g) gstart[g] = i;
      if (i == N_NODES - 1)
        for (int g = bb + 1; g <= NUM_GRAPHS; ++g) gstart[g] = N_NODES;
    }
  } else {
    int i = ((b - NB_NODES) * 256 + threadIdx.x) * 4;
    if (i < N_NODES * D) {
      float4 f = *(const float4*)&x[i];
      ushort4 o = make_ushort4(f2b(f.x), f2b(f.y), f2b(f.z), f2b(f.w));
      *(ushort4*)&xb[i] = o;
    }
  }
}

// ---------------- CSR build ----------------

__global__ void k_count(const int* __restrict__ dst, int* __restrict__ deg) {
  int e = blockIdx.x * 256 + threadIdx.x;
  if (e < N_EDGES) atomicAdd(&deg[dst[e]], 1);
}

__global__ void k_scan1(const int* __restrict__ deg, int* __restrict__ bsum) {
  __shared__ int s[256];
  int t = threadIdx.x;
  int i = blockIdx.x * 256 + t;
  s[t] = (i < N_NODES) ? deg[i] : 0;
  __syncthreads();
  for (int off = 128; off > 0; off >>= 1) {
    if (t < off) s[t] += s[t + off];
    __syncthreads();
  }
  if (t == 0) bsum[blockIdx.x] = s[0];
}

__global__ void k_scan2(int* __restrict__ bsum, int nb) {
  __shared__ int s[256];
  int t = threadIdx.x;
  int v = (t < nb) ? bsum[t] : 0;
  s[t] = v;
  __syncthreads();
  for (int off = 1; off < 256; off <<= 1) {
    int add = (t >= off) ? s[t - off] : 0;
    __syncthreads();
    s[t] += add;
    __syncthreads();
  }
  if (t < nb) bsum[t] = s[t] - v;  // exclusive
}

__global__ void k_scan3(const int* __restrict__ deg, const int* __restrict__ bsum,
                        int* __restrict__ rowptr, int* __restrict__ pos) {
  __shared__ int s[256];
  int t = threadIdx.x;
  int i = blockIdx.x * 256 + t;
  int v = (i < N_NODES) ? deg[i] : 0;
  s[t] = v;
  __syncthreads();
  for (int off = 1; off < 256; off <<= 1) {
    int add = (t >= off) ? s[t - off] : 0;
    __syncthreads();
    s[t] += add;
    __syncthreads();
  }
  int excl = s[t] - v + bsum[blockIdx.x];
  if (i < N_NODES) { rowptr[i] = excl; pos[i] = excl; }
  if (i == N_NODES - 1) rowptr[N_NODES] = excl + v;
}

__global__ void k_bucket(const int* __restrict__ src, const int* __restrict__ dst,
                         int* __restrict__ pos, int* __restrict__ esrc) {
  int e = blockIdx.x * 256 + threadIdx.x;
  if (e < N_EDGES) {
    int slot = atomicAdd(&pos[dst[e]], 1);
    esrc[slot] = src[e];
  }
}

// ---------------- mean aggregation (bf16 gather, one wave per node) ----------------

__global__ __launch_bounds__(256) void k_agg(
    const unsigned short* __restrict__ xb, const int* __restrict__ rowptr,
    const int* __restrict__ esrc, unsigned short* __restrict__ aggb) {
  int node = (blockIdx.x * 256 + threadIdx.x) >> 6;
  int lane = threadIdx.x & 63;
  if (node >= N_NODES) return;
  int beg = rowptr[node], end = rowptr[node + 1];
  float ax = 0.f, ay = 0.f;
  int e = beg;
  for (; e + 4 <= end; e += 4) {
    unsigned int p0 = *(const unsigned int*)&xb[(size_t)esrc[e] * D + lane * 2];
    unsigned int p1 = *(const unsigned int*)&xb[(size_t)esrc[e + 1] * D + lane * 2];
    unsigned int p2 = *(const unsigned int*)&xb[(size_t)esrc[e + 2] * D + lane * 2];
    unsigned int p3 = *(const unsigned int*)&xb[(size_t)esrc[e + 3] * D + lane * 2];
    ax += blo(p0) + blo(p1) + blo(p2) + blo(p3);
    ay += bhi(p0) + bhi(p1) + bhi(p2) + bhi(p3);
  }
  for (; e < end; ++e) {
    unsigned int p = *(const unsigned int*)&xb[(size_t)esrc[e] * D + lane * 2];
    ax += blo(p);
    ay += bhi(p);
  }
  float inv = 1.f / fmaxf((float)(end - beg), 1.f);
  unsigned int o = (unsigned int)f2b(ax * inv) | ((unsigned int)f2b(ay * inv) << 16);
  *(unsigned int*)&aggb[(size_t)node * D + lane * 2] = o;
}

// ---------------- MFMA GEMM: Yb = relu([Ab|Xb] @ [Wl|Wr]^T) as bf16 ----------------
// No __restrict__ on Ab/Yb: layer 2 aliases them (per-block same rows only).

__global__ __launch_bounds__(512) void k_gemm(
    const unsigned short* Ab, const unsigned short* __restrict__ Xb,
    const float* __restrict__ Wl, const float* __restrict__ Wr,
    unsigned short* Yb) {
  __shared__ unsigned short Wlds[32768];  // 64KB: weights [j][k] bf16, XOR-swizzled
  const int tid = threadIdx.x;
  const int w = tid >> 6, lane = tid & 63;
  const int lr = lane & 15, lh = lane >> 4;
  const int row0 = blockIdx.x * BM;
  const int row = row0 + w * 16 + lr;

  // A fragments: row `row`, k in [0,256): first half Ab, second half Xb
  bf16x8 a[8];
  if (row < N_NODES) {
    const unsigned short* ar = Ab + (size_t)row * D;
    const unsigned short* xr = Xb + (size_t)row * D;
#pragma unroll
    for (int kk = 0; kk < 4; ++kk)
      a[kk] = *(const bf16x8*)(ar + kk * 32 + lh * 8);
#pragma unroll
    for (int kk = 0; kk < 4; ++kk)
      a[4 + kk] = *(const bf16x8*)(xr + kk * 32 + lh * 8);
  } else {
#pragma unroll
    for (int kk = 0; kk < 8; ++kk)
      a[kk] = (bf16x8){0, 0, 0, 0, 0, 0, 0, 0};
  }

  // stage combined weight row j: k<128 from Wl, k>=128 from Wr; swizzle byte^=(j&7)<<4
  {
    int j = tid >> 2, quarter = tid & 3;
    const float* srcp = (quarter < 2) ? (Wl + j * D + quarter * 64)
                                      : (Wr + j * D + (quarter - 2) * 64);
#pragma unroll
    for (int q = 0; q < 8; ++q) {
      float4 f0 = *(const float4*)(srcp + q * 8);
      float4 f1 = *(const float4*)(srcp + q * 8 + 4);
      bf16x8 wv;
      wv[0] = (short)f2b(f0.x); wv[1] = (short)f2b(f0.y);
      wv[2] = (short)f2b(f0.z); wv[3] = (short)f2b(f0.w);
      wv[4] = (short)f2b(f1.x); wv[5] = (short)f2b(f1.y);
      wv[6] = (short)f2b(f1.z); wv[7] = (short)f2b(f1.w);
      int byteofs = j * 512 + ((quarter * 128 + q * 16) ^ ((j & 7) << 4));
      *(bf16x8*)((char*)Wlds + byteofs) = wv;
    }
  }
  __syncthreads();

  f32x4 acc[8];
#pragma unroll
  for (int jt = 0; jt < 8; ++jt) acc[jt] = (f32x4){0.f, 0.f, 0.f, 0.f};

#pragma unroll
  for (int jt = 0; jt < 8; ++jt) {
    int jj = jt * 16 + lr;
    const char* wbase = (const char*)Wlds + jj * 512;
    int sw = (jj & 7) << 4;
#pragma unroll
    for (int kk = 0; kk < 8; ++kk) {
      bf16x8 b = *(const bf16x8*)(wbase + ((kk * 64 + lh * 16) ^ sw));
      acc[jt] = __builtin_amdgcn_mfma_f32_16x16x32_bf16(a[kk], b, acc[jt], 0, 0, 0);
    }
  }

  __syncthreads();  // all waves done reading weights; reuse LDS for output tile
  // write relu(acc) as bf16 tile [128 rows][128 cols], swizzled
#pragma unroll
  for (int jt = 0; jt < 8; ++jt) {
#pragma unroll
    for (int r = 0; r < 4; ++r) {
      int rl = w * 16 + lh * 4 + r;
      int col = jt * 16 + lr;
      float v = acc[jt][r];
      v = v > 0.f ? v : 0.f;
      int byteofs = rl * 256 + ((col * 2) ^ ((rl & 7) << 4));
      *(unsigned short*)((char*)Wlds + byteofs) = f2b(v);
    }
  }
  __syncthreads();
  // coalesced bf16x8 stores
  {
    int rl = tid >> 2, c0 = (tid & 3) * 64;  // c0 in bytes
    int grow = row0 + rl;
    if (grow < N_NODES) {
#pragma unroll
      for (int cc = 0; cc < 4; ++cc) {
        int byteofs = rl * 256 + ((c0 + cc * 16) ^ ((rl & 7) << 4));
        bf16x8 v = *(const bf16x8*)((char*)Wlds + byteofs);
        *(bf16x8*)&Yb[(size_t)grow * D + (c0 + cc * 16) / 2] = v;
      }
    }
  }
}

// ---------------- segment-max pool (bf16 in, fp32 out) ----------------

__global__ __launch_bounds__(256) void k_pool(
    const unsigned short* __restrict__ x1b, const unsigned short* __restrict__ x2b,
    const int* __restrict__ gstart, float* __restrict__ out) {
  int g = blockIdx.x, tid = threadIdx.x;
  int beg = gstart[g], end = gstart[g + 1];
  const unsigned short* base = (tid < D) ? (x1b + tid) : (x2b + (tid - D));
  float m = 0.f;  // relu >= 0; empty graph -> 0 matches isfinite guard
  int r = beg;
  for (; r + 4 <= end; r += 4) {
    float a = __uint_as_float((unsigned int)base[(size_t)r * D] << 16);
    float b = __uint_as_float((unsigned int)base[(size_t)(r + 1) * D] << 16);
    float c = __uint_as_float((unsigned int)base[(size_t)(r + 2) * D] << 16);
    float d = __uint_as_float((unsigned int)base[(size_t)(r + 3) * D] << 16);
    m = fmaxf(m, fmaxf(fmaxf(a, b), fmaxf(c, d)));
  }
  for (; r < end; ++r)
    m = fmaxf(m, __uint_as_float((unsigned int)base[(size_t)r * D] << 16));
  out[g * (2 * D) + tid] = m;
}

// ---------------- launch ----------------

extern "C" void kernel_launch(void* const* d_in, const int* in_sizes, int n_in,
                              void* d_out, int out_size, void* d_ws, size_t ws_size,
                              hipStream_t stream) {
  const float* x = (const float*)d_in[0];
  const int* ei = (const int*)d_in[1];
  const int* src = ei;               // edge_index[0]
  const int* dst = ei + N_EDGES;     // edge_index[1]
  const int* batch = (const int*)d_in[2];
  const float* Wl1 = (const float*)d_in[3];
  const float* Wr1 = (const float*)d_in[4];
  const float* Wl2 = (const float*)d_in[5];
  const float* Wr2 = (const float*)d_in[6];
  float* out = (float*)d_out;

  char* ws = (char*)d_ws;
  size_t off = 0;
  auto alloc = [&](size_t bytes) -> void* {
    void* p = ws + off;
    off += (bytes + 511) & ~(size_t)511;
    return p;
  };
  int* deg = (int*)alloc((size_t)N_NODES * 4);
  int* rowptr = (int*)alloc((size_t)(N_NODES + 1) * 4);
  int* pos = (int*)alloc((size_t)N_NODES * 4);
  int* bsum = (int*)alloc(256 * 4);
  int* gstart = (int*)alloc((size_t)(NUM_GRAPHS + 1) * 4);
  int* esrc = (int*)alloc((size_t)N_EDGES * 4);
  unsigned short* xb = (unsigned short*)alloc((size_t)N_NODES * D * 2);
  unsigned short* aggb = (unsigned short*)alloc((size_t)N_NODES * D * 2);  // agg1, agg2, then x2
  unsigned short* x1b = (unsigned short*)alloc((size_t)N_NODES * D * 2);
  (void)ws_size; (void)in_sizes; (void)n_in; (void)out_size;

  // prep: zero deg + ranges + cvt, fused (no runtime fillBuffer in the graph)
  k_prep<<<NB_NODES + CVT_BLOCKS, 256, 0, stream>>>(x, xb, batch, gstart, deg);

  k_count<<<(N_EDGES + 255) / 256, 256, 0, stream>>>(dst, deg);
  k_scan1<<<NB_NODES, 256, 0, stream>>>(deg, bsum);
  k_scan2<<<1, 256, 0, stream>>>(bsum, NB_NODES);
  k_scan3<<<NB_NODES, 256, 0, stream>>>(deg, bsum, rowptr, pos);
  k_bucket<<<(N_EDGES + 255) / 256, 256, 0, stream>>>(src, dst, pos, esrc);

  int agg_blocks = (N_NODES * 64 + 255) / 256;
  int gemm_blocks = (N_NODES + BM - 1) / BM;  // 391

  // layer 1
  k_agg<<<agg_blocks, 256, 0, stream>>>(xb, rowptr, esrc, aggb);
  k_gemm<<<gemm_blocks, 512, 0, stream>>>(aggb, xb, Wl1, Wr1, x1b);
  // layer 2: aggb reused for agg2, then x2 written in place (per-block same rows)
  k_agg<<<agg_blocks, 256, 0, stream>>>(x1b, rowptr, esrc, aggb);
  k_gemm<<<gemm_blocks, 512, 0, stream>>>(aggb, x1b, Wl2, Wr2, aggb);
  // pool: x1 -> cols [0,128), x2(=aggb) -> cols [128,256)
  k_pool<<<NUM_GRAPHS, 256, 0, stream>>>(x1b, aggb, gstart, out);
}